// Round 12
// baseline (256.717 us; speedup 1.0000x reference)
//
#include <hip/hip_runtime.h>
#include <math.h>

// NeighborList: P = N*(N-1)/2 triu pairs, minimum-image distance, cutoff mask.
// out layout (float32, concatenated): [P] pair_i, [P] pair_j, [P*3] pair_diff, [P] pair_dist
//
// R12: region-sequential passes. Each block owns a CONTIGUOUS 4096-quad chunk
// and sweeps it 4 times, writing exactly ONE output region per pass (i, j, r,
// then d). Per-CU store traffic is temporally single-stream and sequential —
// the same pattern as the 6.7 TB/s fill kernel — instead of interleaving 4
// regions per iteration (R8/R11 plateau at 5.15 TB/s). Pair values are
// recomputed per pass: R7 proved compute is cheap/hideable (~15us per sweep).
// Carried: int32+f32 solve_ij, reciprocal-mul min-image (rint-safe: flips
// only possible near |delta|~box/2 where the pair is masked either way),
// diag-cell fast path (off-axis terms are d - s*0 == d bit-exactly),
// vectorized j-side dwordx4 gathers (R10).

#define NL_CUTOFF 5.0f
#define QPB 4096            // quads per block (contiguous chunk)
#define BLOCK 256

typedef float f32x4 __attribute__((ext_vector_type(4)));

// i,j from linear triu pair index p (int32 domain: P < 2^31).
__device__ __forceinline__ void solve_ij(int p, int N, int& io, int& jo) {
    const int A = 2 * N - 1;
    const int disc = A * A - 8 * p;                 // exact, >= 9
    const float sd = __fsqrt_rn((float)disc);
    int ii = (int)(__fmul_rn(__fsub_rn((float)A, sd), 0.5f));
    if (ii < 0) ii = 0;
    if (ii > N - 2) ii = N - 2;
    while (ii > 0 && ((ii * (A - ii)) >> 1) > p) --ii;
    while ((((ii + 1) * (A - ii - 1)) >> 1) <= p) ++ii;
    io = ii;
    jo = p - ((ii * (A - ii)) >> 1) + ii + 1;
}

struct CellC {
    float r0x, r0y, r0z, rc0;
    float r1x, r1y, r1z, rc1;
    float r2x, r2y, r2z, rc2;
};

template <bool DIAG>
__device__ __forceinline__ void pair_compute(
    float xi, float yi, float zi, float xj, float yj, float zj,
    const CellC& c, float fi, float fj,
    float& oi, float& oj, float& odx, float& ody, float& odz, float& orr)
{
    float dx = __fsub_rn(xi, xj);
    float dy = __fsub_rn(yi, yj);
    float dz = __fsub_rn(zi, zj);

    if (DIAG) {
        // diagonal cell: off-axis updates are d - s*0 == d bit-exactly
        float s = rintf(__fmul_rn(dz, c.rc2));
        dz = __fsub_rn(dz, __fmul_rn(s, c.r2z));
        s = rintf(__fmul_rn(dy, c.rc1));
        dy = __fsub_rn(dy, __fmul_rn(s, c.r1y));
        s = rintf(__fmul_rn(dx, c.rc0));
        dx = __fsub_rn(dx, __fmul_rn(s, c.r0x));
    } else {
        float s = rintf(__fmul_rn(dz, c.rc2));
        dx = __fsub_rn(dx, __fmul_rn(s, c.r2x));
        dy = __fsub_rn(dy, __fmul_rn(s, c.r2y));
        dz = __fsub_rn(dz, __fmul_rn(s, c.r2z));

        s = rintf(__fmul_rn(dy, c.rc1));
        dx = __fsub_rn(dx, __fmul_rn(s, c.r1x));
        dy = __fsub_rn(dy, __fmul_rn(s, c.r1y));
        dz = __fsub_rn(dz, __fmul_rn(s, c.r1z));

        s = rintf(__fmul_rn(dx, c.rc0));
        dx = __fsub_rn(dx, __fmul_rn(s, c.r0x));
        dy = __fsub_rn(dy, __fmul_rn(s, c.r0y));
        dz = __fsub_rn(dz, __fmul_rn(s, c.r0z));
    }

    float ss = __fadd_rn(__fadd_rn(__fmul_rn(dx, dx), __fmul_rn(dy, dy)),
                         __fmul_rn(dz, dz));
    float r = __fsqrt_rn(ss);      // correctly rounded: mask boundary bit-exact
    bool m = (r < NL_CUTOFF);

    oi  = m ? fi : -1.0f;
    oj  = m ? fj : -1.0f;
    odx = m ? dx : 0.0f;
    ody = m ? dy : 0.0f;
    odz = m ? dz : 0.0f;
    orr = m ? r  : 0.0f;
}

// compute all outputs for quad q (4 pairs); per-pass callers DCE what they
// don't store.
template <bool DIAG>
__device__ __forceinline__ void quad_vals(
    const float* __restrict__ xyz, const CellC& c, long long q, int N,
    float* oia, float* oja, float* ora, float* od)
{
    int i, j;
    solve_ij((int)(q << 2), N, i, j);

    if (j + 3 <= N - 1) {
        const float xi = xyz[3 * i + 0], yi = xyz[3 * i + 1], zi = xyz[3 * i + 2];
        const float fi = (float)i, fj = (float)j;

        const float* jb = xyz + 3 * j;
        f32x4 va, vb, vc;
        __builtin_memcpy(&va, jb + 0, 16);
        __builtin_memcpy(&vb, jb + 4, 16);
        __builtin_memcpy(&vc, jb + 8, 16);
        const float jx[4] = {va.x, va.w, vb.z, vc.y};
        const float jy[4] = {va.y, vb.x, vb.w, vc.z};
        const float jz[4] = {va.z, vb.y, vc.x, vc.w};
#pragma unroll
        for (int k = 0; k < 4; ++k) {
            pair_compute<DIAG>(xi, yi, zi, jx[k], jy[k], jz[k],
                               c, fi, fj + (float)k,
                               oia[k], oja[k], od[3 * k + 0], od[3 * k + 1],
                               od[3 * k + 2], ora[k]);
        }
    } else {
        int ii = i, jj = j;
#pragma unroll
        for (int k = 0; k < 4; ++k) {
            pair_compute<DIAG>(xyz[3 * ii + 0], xyz[3 * ii + 1], xyz[3 * ii + 2],
                               xyz[3 * jj + 0], xyz[3 * jj + 1], xyz[3 * jj + 2],
                               c, (float)ii, (float)jj,
                               oia[k], oja[k], od[3 * k + 0], od[3 * k + 1],
                               od[3 * k + 2], ora[k]);
            if (++jj >= N) { ++ii; jj = ii + 1; }
        }
    }
}

template <bool DIAG>
__device__ __forceinline__ void nl_body(
    const float* __restrict__ xyz, const CellC& c,
    float* __restrict__ out, long long P, int N)
{
    float* __restrict__ out_i = out;
    float* __restrict__ out_j = out + P;
    float* __restrict__ out_d = out + 2 * P;   // [P,3] row-major
    float* __restrict__ out_r = out + 5 * P;

    const long long nquad = P >> 2;
    const long long qbase = (long long)blockIdx.x * QPB;
    const int       tid   = (int)threadIdx.x;

    float oia[4], oja[4], ora[4], od[12];

    // pass 1: pair_i — each block streams 64KB sequentially
    for (int it = 0; it < QPB / BLOCK; ++it) {
        const long long q = qbase + it * BLOCK + tid;
        if (q >= nquad) break;
        quad_vals<DIAG>(xyz, c, q, N, oia, oja, ora, od);
        ((float4*)out_i)[q] = make_float4(oia[0], oia[1], oia[2], oia[3]);
    }
    // pass 2: pair_j
    for (int it = 0; it < QPB / BLOCK; ++it) {
        const long long q = qbase + it * BLOCK + tid;
        if (q >= nquad) break;
        quad_vals<DIAG>(xyz, c, q, N, oia, oja, ora, od);
        ((float4*)out_j)[q] = make_float4(oja[0], oja[1], oja[2], oja[3]);
    }
    // pass 3: pair_dist
    for (int it = 0; it < QPB / BLOCK; ++it) {
        const long long q = qbase + it * BLOCK + tid;
        if (q >= nquad) break;
        quad_vals<DIAG>(xyz, c, q, N, oia, oja, ora, od);
        ((float4*)out_r)[q] = make_float4(ora[0], ora[1], ora[2], ora[3]);
    }
    // pass 4: pair_diff — 3 float4 per thread; the 3-instr group fully covers
    // the wave's 3KB window (single-region, L2-merged)
    for (int it = 0; it < QPB / BLOCK; ++it) {
        const long long q = qbase + it * BLOCK + tid;
        if (q >= nquad) break;
        quad_vals<DIAG>(xyz, c, q, N, oia, oja, ora, od);
        float4* dd = (float4*)(out_d + 12 * q);
        dd[0] = make_float4(od[0], od[1],  od[2],  od[3]);
        dd[1] = make_float4(od[4], od[5],  od[6],  od[7]);
        dd[2] = make_float4(od[8], od[9],  od[10], od[11]);
    }

    // tail (P % 4 != 0 safety; empty for N=8192): block 0 handles it
    if (blockIdx.x == 0) {
        for (long long p = (nquad << 2) + tid; p < P; p += BLOCK) {
            int i, j;
            solve_ij((int)p, N, i, j);
            float oi, oj, dx, dy, dz, rr;
            pair_compute<DIAG>(xyz[3 * i + 0], xyz[3 * i + 1], xyz[3 * i + 2],
                               xyz[3 * j + 0], xyz[3 * j + 1], xyz[3 * j + 2],
                               c, (float)i, (float)j, oi, oj, dx, dy, dz, rr);
            out_i[p] = oi;
            out_j[p] = oj;
            out_d[3 * p + 0] = dx;
            out_d[3 * p + 1] = dy;
            out_d[3 * p + 2] = dz;
            out_r[p] = rr;
        }
    }
}

__global__ __launch_bounds__(256, 8) void nl_kernel(
    const float* __restrict__ xyz,
    const float* __restrict__ cell,
    float* __restrict__ out,
    long long P, int N)
{
    CellC c;
    c.r0x = cell[0]; c.r0y = cell[1]; c.r0z = cell[2];
    c.r1x = cell[3]; c.r1y = cell[4]; c.r1z = cell[5];
    c.r2x = cell[6]; c.r2y = cell[7]; c.r2z = cell[8];
    c.rc0 = __fdiv_rn(1.0f, c.r0x);
    c.rc1 = __fdiv_rn(1.0f, c.r1y);
    c.rc2 = __fdiv_rn(1.0f, c.r2z);

    const bool diag = (c.r0y == 0.0f) && (c.r0z == 0.0f) &&
                      (c.r1x == 0.0f) && (c.r1z == 0.0f) &&
                      (c.r2x == 0.0f) && (c.r2y == 0.0f);

    if (diag) nl_body<true>(xyz, c, out, P, N);
    else      nl_body<false>(xyz, c, out, P, N);
}

extern "C" void kernel_launch(void* const* d_in, const int* in_sizes, int n_in,
                              void* d_out, int out_size, void* d_ws, size_t ws_size,
                              hipStream_t stream) {
    const float* xyz  = (const float*)d_in[0];
    const float* cell = (const float*)d_in[1];
    float* out = (float*)d_out;

    const int       N = in_sizes[0] / 3;
    const long long P = (long long)in_sizes[2];

    const long long nquad = P >> 2;
    int grid = (int)((nquad + QPB - 1) / QPB);
    if (grid < 1) grid = 1;

    nl_kernel<<<grid, BLOCK, 0, stream>>>(xyz, cell, out, P, N);
}

// Round 13
// 156.724 us; speedup vs baseline: 1.6380x; 1.6380x over previous
//
#include <hip/hip_runtime.h>
#include <math.h>

// NeighborList: P = N*(N-1)/2 triu pairs, minimum-image distance, cutoff mask.
// out layout (float32, concatenated): [P] pair_i, [P] pair_j, [P*3] pair_diff, [P] pair_dist
//
// R13 = R8 restored (best measured: 156.5 us). Model (calibrated by R12):
// T ~= write-drain(805MB @ 6.7TB/s = 120us) + launch(~8us) + exposed
// mandatory pair compute (~28us, ~28 f32 ops/pair, exposes ~1:1 vs stores).
// Probed-neutral axes: load coalescing (R6/R10), VALU trims (R7), occupancy
// (R11). Probed-negative: nontemporal stores (R3), memset split (R9),
// region-sequential passes (R12). Win kept: per-wave LDS transpose of the
// diff stream -> all global stores lane-contiguous (R8, +9us).
// Numerics: reciprocal-mul min-image is rint-safe (flips only possible near
// |delta|~box/2 where the pair is masked under either image choice);
// diag-cell fast path skips terms that are d - s*0 == d bit-exactly;
// __fsqrt_rn keeps the dist<5 mask boundary bit-exact vs numpy f32.

#define NL_CUTOFF 5.0f

typedef float f32x4 __attribute__((ext_vector_type(4)));

// i,j from linear triu pair index p (int32 domain: P < 2^31).
__device__ __forceinline__ void solve_ij(int p, int N, int& io, int& jo) {
    const int A = 2 * N - 1;
    const int disc = A * A - 8 * p;                 // exact, >= 9
    const float sd = __fsqrt_rn((float)disc);
    int ii = (int)(__fmul_rn(__fsub_rn((float)A, sd), 0.5f));
    if (ii < 0) ii = 0;
    if (ii > N - 2) ii = N - 2;
    while (ii > 0 && ((ii * (A - ii)) >> 1) > p) --ii;
    while ((((ii + 1) * (A - ii - 1)) >> 1) <= p) ++ii;
    io = ii;
    jo = p - ((ii * (A - ii)) >> 1) + ii + 1;
}

struct CellC {
    float r0x, r0y, r0z, rc0;
    float r1x, r1y, r1z, rc1;
    float r2x, r2y, r2z, rc2;
};

template <bool DIAG>
__device__ __forceinline__ void pair_compute(
    float xi, float yi, float zi, float xj, float yj, float zj,
    const CellC& c, float fi, float fj,
    float& oi, float& oj, float& odx, float& ody, float& odz, float& orr)
{
    float dx = __fsub_rn(xi, xj);
    float dy = __fsub_rn(yi, yj);
    float dz = __fsub_rn(zi, zj);

    if (DIAG) {
        // diagonal cell: off-axis updates are d - s*0 == d bit-exactly
        float s = rintf(__fmul_rn(dz, c.rc2));
        dz = __fsub_rn(dz, __fmul_rn(s, c.r2z));
        s = rintf(__fmul_rn(dy, c.rc1));
        dy = __fsub_rn(dy, __fmul_rn(s, c.r1y));
        s = rintf(__fmul_rn(dx, c.rc0));
        dx = __fsub_rn(dx, __fmul_rn(s, c.r0x));
    } else {
        float s = rintf(__fmul_rn(dz, c.rc2));
        dx = __fsub_rn(dx, __fmul_rn(s, c.r2x));
        dy = __fsub_rn(dy, __fmul_rn(s, c.r2y));
        dz = __fsub_rn(dz, __fmul_rn(s, c.r2z));

        s = rintf(__fmul_rn(dy, c.rc1));
        dx = __fsub_rn(dx, __fmul_rn(s, c.r1x));
        dy = __fsub_rn(dy, __fmul_rn(s, c.r1y));
        dz = __fsub_rn(dz, __fmul_rn(s, c.r1z));

        s = rintf(__fmul_rn(dx, c.rc0));
        dx = __fsub_rn(dx, __fmul_rn(s, c.r0x));
        dy = __fsub_rn(dy, __fmul_rn(s, c.r0y));
        dz = __fsub_rn(dz, __fmul_rn(s, c.r0z));
    }

    float ss = __fadd_rn(__fadd_rn(__fmul_rn(dx, dx), __fmul_rn(dy, dy)),
                         __fmul_rn(dz, dz));
    float r = __fsqrt_rn(ss);      // correctly rounded: mask boundary bit-exact
    bool m = (r < NL_CUTOFF);

    oi  = m ? fi : -1.0f;
    oj  = m ? fj : -1.0f;
    odx = m ? dx : 0.0f;
    ody = m ? dy : 0.0f;
    odz = m ? dz : 0.0f;
    orr = m ? r  : 0.0f;
}

template <bool DIAG>
__device__ __forceinline__ void nl_body(
    const float* __restrict__ xyz, const CellC& c,
    float* __restrict__ out, long long P, int N,
    f32x4* __restrict__ wslab)          // per-wave 192-float4 LDS slab
{
    float* __restrict__ out_i = out;
    float* __restrict__ out_j = out + P;
    float* __restrict__ out_d = out + 2 * P;   // [P,3] row-major
    float* __restrict__ out_r = out + 5 * P;

    const long long nquad  = P >> 2;
    const long long stride = (long long)gridDim.x * blockDim.x;
    const long long tid0   = (long long)blockIdx.x * blockDim.x + threadIdx.x;
    const int       lane   = (int)(threadIdx.x & 63);
    const int       lm     = lane % 3;

    for (long long q = tid0; q < nquad; q += stride) {
        int i, j;
        solve_ij((int)(q << 2), N, i, j);

        float oia[4], oja[4], ora[4], od[12];
        if (j + 3 <= N - 1) {
            const float xi = xyz[3 * i + 0], yi = xyz[3 * i + 1], zi = xyz[3 * i + 2];
            const float fi = (float)i, fj = (float)j;
#pragma unroll
            for (int k = 0; k < 4; ++k) {
                pair_compute<DIAG>(xi, yi, zi,
                                   xyz[3 * (j + k) + 0], xyz[3 * (j + k) + 1],
                                   xyz[3 * (j + k) + 2],
                                   c, fi, fj + (float)k,
                                   oia[k], oja[k], od[3 * k + 0], od[3 * k + 1],
                                   od[3 * k + 2], ora[k]);
            }
        } else {
            int ii = i, jj = j;
#pragma unroll
            for (int k = 0; k < 4; ++k) {
                pair_compute<DIAG>(xyz[3 * ii + 0], xyz[3 * ii + 1], xyz[3 * ii + 2],
                                   xyz[3 * jj + 0], xyz[3 * jj + 1], xyz[3 * jj + 2],
                                   c, (float)ii, (float)jj,
                                   oia[k], oja[k], od[3 * k + 0], od[3 * k + 1],
                                   od[3 * k + 2], ora[k]);
                if (++jj >= N) { ++ii; jj = ii + 1; }
            }
        }

        ((float4*)out_i)[q] = make_float4(oia[0], oia[1], oia[2], oia[3]);
        ((float4*)out_j)[q] = make_float4(oja[0], oja[1], oja[2], oja[3]);
        ((float4*)out_r)[q] = make_float4(ora[0], ora[1], ora[2], ora[3]);

        const f32x4 pd0 = {od[0], od[1], od[2],  od[3]};
        const f32x4 pd1 = {od[4], od[5], od[6],  od[7]};
        const f32x4 pd2 = {od[8], od[9], od[10], od[11]};

        const long long qw = q - lane;              // wave-uniform base quad
        if (qw + 63 < nquad) {
            // wave fully active: LDS transpose -> lane-contiguous dd stores.
            // write slot = 3*lane + (m+lane)%3 (rotation keeps conflicts <=3-way)
            int s0 = lm;
            int s1 = lm + 1; if (s1 >= 3) s1 -= 3;
            int s2 = lm + 2; if (s2 >= 3) s2 -= 3;
            wslab[3 * lane + s0] = pd0;
            wslab[3 * lane + s1] = pd1;
            wslab[3 * lane + s2] = pd2;
            __builtin_amdgcn_wave_barrier();
            f32x4* __restrict__ dd4 = (f32x4*)out_d;   // 16B-aligned (P%4==0)
#pragma unroll
            for (int m = 0; m < 3; ++m) {
                const int f  = m * 64 + lane;          // flat float4 idx in wave tile
                const int r  = f / 3;                  // owner lane
                const int cc = f - 3 * r;              // component
                int s = cc + r % 3; if (s >= 3) s -= 3;
                const f32x4 v = wslab[3 * r + s];
                dd4[3 * qw + f] = v;                   // contiguous 1KB/instr
            }
            __builtin_amdgcn_wave_barrier();
        } else {
            float4* dd = (float4*)(out_d + 12 * q);
            dd[0] = make_float4(od[0], od[1],  od[2],  od[3]);
            dd[1] = make_float4(od[4], od[5],  od[6],  od[7]);
            dd[2] = make_float4(od[8], od[9],  od[10], od[11]);
        }
    }

    // tail (P % 4 != 0 safety; P divisible by 4 for N=8192)
    for (long long p = (nquad << 2) + tid0; p < P; p += stride) {
        int i, j;
        solve_ij((int)p, N, i, j);
        float oi, oj, dx, dy, dz, rr;
        pair_compute<DIAG>(xyz[3 * i + 0], xyz[3 * i + 1], xyz[3 * i + 2],
                           xyz[3 * j + 0], xyz[3 * j + 1], xyz[3 * j + 2],
                           c, (float)i, (float)j, oi, oj, dx, dy, dz, rr);
        out_i[p] = oi;
        out_j[p] = oj;
        out_d[3 * p + 0] = dx;
        out_d[3 * p + 1] = dy;
        out_d[3 * p + 2] = dz;
        out_r[p] = rr;
    }
}

__global__ __launch_bounds__(256) void nl_kernel(
    const float* __restrict__ xyz,
    const float* __restrict__ cell,
    float* __restrict__ out,
    long long P, int N)
{
    __shared__ f32x4 slab[4][192];     // one 3KB slab per wave (block = 4 waves)

    CellC c;
    c.r0x = cell[0]; c.r0y = cell[1]; c.r0z = cell[2];
    c.r1x = cell[3]; c.r1y = cell[4]; c.r1z = cell[5];
    c.r2x = cell[6]; c.r2y = cell[7]; c.r2z = cell[8];
    c.rc0 = __fdiv_rn(1.0f, c.r0x);
    c.rc1 = __fdiv_rn(1.0f, c.r1y);
    c.rc2 = __fdiv_rn(1.0f, c.r2z);

    const bool diag = (c.r0y == 0.0f) && (c.r0z == 0.0f) &&
                      (c.r1x == 0.0f) && (c.r1z == 0.0f) &&
                      (c.r2x == 0.0f) && (c.r2y == 0.0f);

    const int wid = threadIdx.x >> 6;
    if (diag) nl_body<true>(xyz, c, out, P, N, slab[wid]);
    else      nl_body<false>(xyz, c, out, P, N, slab[wid]);
}

extern "C" void kernel_launch(void* const* d_in, const int* in_sizes, int n_in,
                              void* d_out, int out_size, void* d_ws, size_t ws_size,
                              hipStream_t stream) {
    const float* xyz  = (const float*)d_in[0];
    const float* cell = (const float*)d_in[1];
    float* out = (float*)d_out;

    const int       N = in_sizes[0] / 3;
    const long long P = (long long)in_sizes[2];

    const int block = 256;
    long long nquad = P >> 2;
    long long blocks_needed = (nquad + block - 1) / block;
    int grid = (int)(blocks_needed < 2048 ? (blocks_needed > 0 ? blocks_needed : 1)
                                          : 2048);

    nl_kernel<<<grid, block, 0, stream>>>(xyz, cell, out, P, N);
}